// Round 9
// baseline (600.633 us; speedup 1.0000x reference)
//
#include <hip/hip_runtime.h>
#include <hip/hip_bf16.h>

typedef __hip_bfloat16 bf16;
typedef __attribute__((ext_vector_type(8))) short short8;
typedef __attribute__((ext_vector_type(4))) float f32x4;

#define MODEL_DIM 2048
#define INNER     4096
#define NHEADS    64
#define HEAD_DIM  64
#define STATE_DIM 128
#define IN_PROJ   4416
#define NPAD      4608        /* padded to 24*192 for the in-proj GEMM grid */
#define BSZ       2
#define SEQ       4096
#define CHUNKL    64
#define NTOK      (BSZ*SEQ)      /* 8192 */
#define NCHUNK    (SEQ/CHUNKL)   /* 64 */

#define WAITV0() asm volatile("s_waitcnt vmcnt(0)" ::: "memory")
#define BAR()    __builtin_amdgcn_s_barrier()
#define SCHEDB() __builtin_amdgcn_sched_barrier(0)
#define WAITLG(N) do { asm volatile("s_waitcnt lgkmcnt(" #N ")" ::: "memory"); SCHEDB(); } while (0)

// swizzle: XOR the 16B-slot index (bits 4-6) with row&7 (bits 7-9). Involution.
#define SWZ(x) ((x) ^ ((((x) >> 7) & 7) << 4))

// ---------------- helpers ----------------
static __device__ __forceinline__ void gload_lds16(const bf16* g, bf16* l) {
  __builtin_amdgcn_global_load_lds((const __attribute__((address_space(1))) void*)g,
                                   (__attribute__((address_space(3))) void*)l, 16, 0, 0);
}

static __device__ __forceinline__ unsigned lds_u32(const void* p) {
  return (unsigned)(unsigned long long)(const __attribute__((address_space(3))) char*)p;
}

static __device__ __forceinline__ short8 ds_read128(unsigned addr) {
  short8 r;
  asm volatile("ds_read_b128 %0, %1" : "=v"(r) : "v"(addr));
  return r;
}

// stage one 8KB unit (64 rows x 64 cols bf16): 1 gload_lds per thread (512 thr x 16B).
// LDS dest linear; global source pre-permuted by the (involutory) swizzle.
static __device__ __forceinline__ void stage_unit(const bf16* __restrict__ P, int K,
                                                  int blockRow, int kt,
                                                  char* region, int unit, int t) {
  int o = unit * 8192 + (t << 4);
  int lb = SWZ(o);
  int row = lb >> 7, colb = lb & 127;
  gload_lds16(P + (size_t)(blockRow + row) * K + kt + (colb >> 1), (bf16*)(region + o));
}

// MFMA chunk: a-array av (4 m-frags at acc rows MBASE..MBASE+3) x b[nf] for nf in [NLO,NHI)
#define MFMA_CH(av, MBASE, NLO, NHI)                                                    \
  __builtin_amdgcn_s_setprio(1);                                                        \
  _Pragma("unroll") for (int mf = 0; mf < 4; ++mf)                                      \
    _Pragma("unroll") for (int nf = (NLO); nf < (NHI); ++nf)                            \
      _Pragma("unroll") for (int ks = 0; ks < 2; ++ks)                                  \
        acc[(MBASE) + mf][nf] = __builtin_amdgcn_mfma_f32_16x16x32_bf16(                \
            av[mf][ks], b[nf][ks], acc[(MBASE) + mf][nf], 0, 0, 0);                     \
  __builtin_amdgcn_s_setprio(0);

// ---------------- 256xBN / BK=64 / 8-wave / cross-tile read-ahead GEMM core ----------------
// Two barriers per tile. a-lo of tile t+1 is read into dedicated regs (aN) mid-tile t,
// draining under tile t's final MFMA chunk. All waits counted; see ledger in commit msg.
template<int BN>
static __device__ __forceinline__ void gemm_core2(
    const bf16* __restrict__ Ag, const bf16* __restrict__ Bg,
    int K, int NT, int bm, int bn, char* lds, f32x4 (&acc)[8][BN / 64]) {
  constexpr int NR = BN / 64;             // B frags per wave == B 64-row units
  constexpr int BB = 32768 + NR * 8192;   // bytes per (A+B) buffer
  const int t = threadIdx.x;
  const int lane = t & 63;
  const int wid = t >> 6, wm = wid >> 2, wn = wid & 3;
  const unsigned x16 = (unsigned)(lane & 7) << 4;     // read-side swizzle XOR
  const unsigned kb0 = (unsigned)(lane >> 4) << 4;    // 0,16,32,48
  const unsigned ldsB = lds_u32(lds);
  const unsigned aRow0 = (unsigned)(wm * 128 + (lane & 15)) * 128;
  const unsigned bRow0 = (unsigned)(wn * (BN / 4) + (lane & 15)) * 128;

  // prologue: tile 0 -> buf0, then pre-read a-lo(0)
#pragma unroll
  for (int u = 0; u < 4; ++u) stage_unit(Ag, K, bm, 0, lds, u, t);
#pragma unroll
  for (int u = 0; u < NR; ++u) stage_unit(Bg, K, bn, 0, lds + 32768, u, t);
  WAITV0();
  BAR();

  short8 aN[4][2], ah[4][2], b[NR][2];
#pragma unroll
  for (int mf = 0; mf < 4; ++mf)
#pragma unroll
    for (int ks = 0; ks < 2; ++ks)
      aN[mf][ks] = ds_read128(ldsB + aRow0 + mf * 2048 + (((unsigned)(ks * 64) + kb0) ^ x16));

  for (int tt = 0; tt < NT; ++tt) {
    const unsigned aB  = ldsB + (unsigned)((tt & 1) * BB);
    const unsigned bB  = aB + 32768;
    const unsigned aB1 = ldsB + (unsigned)(((tt + 1) & 1) * BB);
    char* oth = lds + ((tt + 1) & 1) * BB;
    const bool st = (tt + 1 < NT);

    // R1 issue (FIFO): b-lo(4), b-hi(2*(NR-2)), a-hi(8) from current buf
#pragma unroll
    for (int nf = 0; nf < 2; ++nf)
#pragma unroll
      for (int ks = 0; ks < 2; ++ks)
        b[nf][ks] = ds_read128(bB + bRow0 + nf * 2048 + (((unsigned)(ks * 64) + kb0) ^ x16));
#pragma unroll
    for (int nf = 2; nf < NR; ++nf)
#pragma unroll
      for (int ks = 0; ks < 2; ++ks)
        b[nf][ks] = ds_read128(bB + bRow0 + nf * 2048 + (((unsigned)(ks * 64) + kb0) ^ x16));
#pragma unroll
    for (int mf = 0; mf < 4; ++mf)
#pragma unroll
      for (int ks = 0; ks < 2; ++ks)
        ah[mf][ks] = ds_read128(aB + aRow0 + (4 + mf) * 2048 + (((unsigned)(ks * 64) + kb0) ^ x16));

    if (st) {                               // stage t+1 -> other buffer
      const int kt1 = (tt + 1) * 64;
#pragma unroll
      for (int u = 0; u < 4; ++u) stage_unit(Ag, K, bm, kt1, oth, u, t);
#pragma unroll
      for (int u = 0; u < NR; ++u) stage_unit(Bg, K, bn, kt1, oth + 32768, u, t);
    }

    // cA1: aN x b-lo  (needs aN[8 retired] + b-lo[4]; outstanding = 8+R1 - 12)
    if constexpr (NR == 4) WAITLG(12); else WAITLG(10);
    MFMA_CH(aN, 0, 0, 2);
    // cA2: aN x b-hi  (needs b-hi; retired >= 8+4+2*(NR-2))
    WAITLG(8);
    MFMA_CH(aN, 0, 2, NR);

    WAITV0();                               // stage(t+1) landed (issued ~1 chunk ago)
    BAR();                                  // mid barrier: buf(t+1) globally visible
    if (st) {                               // read-ahead a-lo(t+1); drains under cB
#pragma unroll
      for (int mf = 0; mf < 4; ++mf)
#pragma unroll
        for (int ks = 0; ks < 2; ++ks)
          aN[mf][ks] = ds_read128(aB1 + aRow0 + mf * 2048 + (((unsigned)(ks * 64) + kb0) ^ x16));
      WAITLG(8);                            // all R1 retired (only new aN outstanding)
    } else {
      WAITLG(0);
    }
    // cB: a-hi x b-all
    MFMA_CH(ah, 4, 0, NR);
    BAR();                                  // end barrier: buf(t) reads globally retired
  }
}

// in-proj GEMM (BN=192): routed epilogue (x->bf16, B->bf16, C->bf16, dt->f32)
__global__ __launch_bounds__(512, 2)
void gemm_in256(const bf16* __restrict__ A, const bf16* __restrict__ Bw,
                const float* __restrict__ bias, bf16* __restrict__ x_bf,
                bf16* __restrict__ B_bf, bf16* __restrict__ C_bf, float* __restrict__ dtraw) {
  __shared__ char lds[2 * (32768 + 3 * 8192)];
  int nwg = gridDim.x, bid = blockIdx.x;
  int cpx = nwg >> 3;
  int sb = (bid & 7) * cpx + (bid >> 3);       // bijective: nwg % 8 == 0
  int bx = sb % (NPAD / 192), by = sb / (NPAD / 192);
  int bm = by * 256, bn = bx * 192;
  f32x4 acc[8][3] = {};
  gemm_core2<192>(A, Bw, MODEL_DIM, MODEL_DIM / 64, bm, bn, lds, acc);
  const int lane = threadIdx.x & 63, wid = threadIdx.x >> 6;
  const int wm = wid >> 2, wn = wid & 3;
#pragma unroll
  for (int mf = 0; mf < 8; ++mf)
#pragma unroll
    for (int nf = 0; nf < 3; ++nf)
#pragma unroll
      for (int r = 0; r < 4; ++r) {
        int row = bm + wm * 128 + mf * 16 + (lane >> 4) * 4 + r;
        int col = bn + wn * 48 + nf * 16 + (lane & 15);
        float v = acc[mf][nf][r] + ((col < IN_PROJ) ? bias[col] : 0.f);
        if (col < 4096)       x_bf[(size_t)row * 4096 + col]         = __float2bfloat16(v);
        else if (col < 4224)  B_bf[(size_t)row * 128 + (col - 4096)] = __float2bfloat16(v);
        else if (col < 4352)  C_bf[(size_t)row * 128 + (col - 4224)] = __float2bfloat16(v);
        else if (col < 4416)  dtraw[(size_t)row * 64 + (col - 4352)] = v;
      }
}

// out-proj GEMM (BN=256): f32 output + bias
__global__ __launch_bounds__(512, 2)
void gemm_out256(const bf16* __restrict__ A, const bf16* __restrict__ Bw,
                 const float* __restrict__ bias, float* __restrict__ C) {
  __shared__ char lds[2 * (32768 + 4 * 8192)];
  int nwg = gridDim.x, bid = blockIdx.x;
  int cpx = nwg >> 3;
  int sb = (bid & 7) * cpx + (bid >> 3);
  int bx = sb % (MODEL_DIM / 256), by = sb / (MODEL_DIM / 256);
  int bm = by * 256, bn = bx * 256;
  f32x4 acc[8][4] = {};
  gemm_core2<256>(A, Bw, INNER, INNER / 64, bm, bn, lds, acc);
  const int lane = threadIdx.x & 63, wid = threadIdx.x >> 6;
  const int wm = wid >> 2, wn = wid & 3;
#pragma unroll
  for (int mf = 0; mf < 8; ++mf)
#pragma unroll
    for (int nf = 0; nf < 4; ++nf)
#pragma unroll
      for (int r = 0; r < 4; ++r) {
        int row = bm + wm * 128 + mf * 16 + (lane >> 4) * 4 + r;
        int col = bn + wn * 64 + nf * 16 + (lane & 15);
        C[(size_t)row * MODEL_DIM + col] = acc[mf][nf][r] + bias[col];
      }
}

// ---------------- converts ----------------
__global__ __launch_bounds__(256) void conv_f32_to_bf16(const float* __restrict__ src,
                                                        bf16* __restrict__ dst, int n4) {
  int i = blockIdx.x * 256 + threadIdx.x;
  if (i >= n4) return;
  float4 v = *(const float4*)(src + (size_t)i * 4);
  bf16* d = dst + (size_t)i * 4;
  d[0] = __float2bfloat16(v.x); d[1] = __float2bfloat16(v.y);
  d[2] = __float2bfloat16(v.z); d[3] = __float2bfloat16(v.w);
}

__global__ __launch_bounds__(256) void conv_win_pad(const float* __restrict__ W,
                                                    bf16* __restrict__ dst) {
  int i = blockIdx.x * 256 + threadIdx.x;      // over NPAD*2048/4
  int row = (i * 4) >> 11;
  int col = (i * 4) & 2047;
  bf16* d = dst + (size_t)i * 4;
  if (row < IN_PROJ) {
    float4 v = *(const float4*)(W + (size_t)row * 2048 + col);
    d[0] = __float2bfloat16(v.x); d[1] = __float2bfloat16(v.y);
    d[2] = __float2bfloat16(v.z); d[3] = __float2bfloat16(v.w);
  } else {
    bf16 z = __float2bfloat16(0.f);
    d[0] = z; d[1] = z; d[2] = z; d[3] = z;
  }
}

// ---------------- prep: dt tables only ----------------
__global__ __launch_bounds__(256)
void prep_small(const float* __restrict__ dtraw, const float* __restrict__ A_log,
                const float* __restrict__ dt_bias, float* __restrict__ dts,
                float* __restrict__ a_dt) {
  int i = blockIdx.x * 256 + threadIdx.x;      // NTOK*64
  int h = i & 63;
  float z = dtraw[i] + dt_bias[h];
  float dt = (z > 20.f) ? z : log1pf(expf(z));
  dts[i] = dt;
  a_dt[i] = -expf(A_log[h]) * dt;
}

// ---------------- intra-chunk states: states[b][c][h][p][n] (bf16) ----------------
__global__ __launch_bounds__(256)
void ssd_states_kernel(const bf16* __restrict__ x_bf, const bf16* __restrict__ B_bf,
                       const float* __restrict__ dts, const float* __restrict__ a_dt,
                       float* __restrict__ acs_g, bf16* __restrict__ states_g) {
  __shared__ bf16 xT[64 * 64];      // [p][l]
  __shared__ bf16 BdT[128 * 64];    // [n][l]
  __shared__ float acs_s[64];
  int blk = blockIdx.x;             // b*4096 + c*64 + h
  int h = blk & 63, c = (blk >> 6) & 63, b = blk >> 12;
  int t = threadIdx.x, lane = t & 63, wid = t >> 6;
  int tokBase = b * SEQ + c * 64;

  if (t < 64) {
    float v = a_dt[(size_t)(tokBase + t) * 64 + h];
#pragma unroll
    for (int d = 1; d < 64; d <<= 1) { float o = __shfl_up(v, d); if (t >= d) v += o; }
    acs_s[t] = v;
    acs_g[(((size_t)(b * 64 + c)) * 64 + h) * 64 + t] = v;
  }
  __syncthreads();
  float acs63 = acs_s[63];

#pragma unroll
  for (int i = 0; i < 2; ++i) {                         // x transpose (+ dt scale)
    int chunk = t + i * 256;
    int l = chunk >> 3, p0 = (chunk & 7) * 8;
    float dtv = dts[(size_t)(tokBase + l) * 64 + h];
    short8 vv = *(const short8*)(x_bf + (size_t)(tokBase + l) * 4096 + h * 64 + p0);
    const bf16* pv = (const bf16*)&vv;
#pragma unroll
    for (int j = 0; j < 8; ++j)
      xT[(p0 + j) * 64 + l] = __float2bfloat16(__bfloat162float(pv[j]) * dtv);
  }
#pragma unroll
  for (int i = 0; i < 4; ++i) {                         // B*decay transpose
    int chunk = t + i * 256;
    int l = chunk >> 4, n0 = (chunk & 15) * 8;
    float dec = expf(acs63 - acs_s[l]);
    short8 vv = *(const short8*)(B_bf + (size_t)(tokBase + l) * 128 + n0);
    const bf16* pv = (const bf16*)&vv;
#pragma unroll
    for (int j = 0; j < 8; ++j)
      BdT[(n0 + j) * 64 + l] = __float2bfloat16(__bfloat162float(pv[j]) * dec);
  }
  __syncthreads();

  int pBase = (wid >> 1) * 32, nBase = (wid & 1) * 64;
  f32x4 acc[2][4] = {};
#pragma unroll
  for (int ks = 0; ks < 2; ++ks) {
    short8 a[2], bb[4];
#pragma unroll
    for (int mi = 0; mi < 2; ++mi)
      a[mi] = *(const short8*)(xT + (pBase + mi * 16 + (lane & 15)) * 64 + ks * 32 + (lane >> 4) * 8);
#pragma unroll
    for (int ni = 0; ni < 4; ++ni)
      bb[ni] = *(const short8*)(BdT + (nBase + ni * 16 + (lane & 15)) * 64 + ks * 32 + (lane >> 4) * 8);
#pragma unroll
    for (int mi = 0; mi < 2; ++mi)
#pragma unroll
      for (int ni = 0; ni < 4; ++ni)
        acc[mi][ni] = __builtin_amdgcn_mfma_f32_16x16x32_bf16(a[mi], bb[ni], acc[mi][ni], 0, 0, 0);
  }
  size_t sbase = ((size_t)((b * 64 + c) * 64 + h)) * 64 * 128;
#pragma unroll
  for (int mi = 0; mi < 2; ++mi)
#pragma unroll
    for (int ni = 0; ni < 4; ++ni)
#pragma unroll
      for (int r = 0; r < 4; ++r) {
        int p = pBase + mi * 16 + (lane >> 4) * 4 + r;
        int n = nBase + ni * 16 + (lane & 15);
        states_g[sbase + (size_t)p * 128 + n] = __float2bfloat16(acc[mi][ni][r]);
      }
}

// ---------------- inter-chunk scan (in-place states -> states_prev, bf16) ----------------
__global__ __launch_bounds__(256)
void ssd_scan_kernel(bf16* __restrict__ states_g, const float* __restrict__ acs_g,
                     float* __restrict__ out_fs) {
  int blk = blockIdx.x;             // (b*64 + h)*4 + q
  int q = blk & 3, bh = blk >> 2;
  int b = bh >> 6, h = bh & 63;
  int t = threadIdx.x;
  int eb = q * 2048 + t;
  float S[8];
#pragma unroll
  for (int i = 0; i < 8; ++i) S[i] = 0.f;
  for (int c = 0; c < 64; ++c) {
    size_t base = ((size_t)((b * 64 + c) * 64 + h)) * 8192;
    float dfac = expf(acs_g[(((size_t)(b * 64 + c)) * 64 + h) * 64 + 63]);
#pragma unroll
    for (int i = 0; i < 8; ++i) {
      int e = eb + i * 256;
      float cs = __bfloat162float(states_g[base + e]);
      states_g[base + e] = __float2bfloat16(S[i]);
      S[i] = dfac * S[i] + cs;
    }
  }
  size_t ob = (size_t)bh * 8192;
#pragma unroll
  for (int i = 0; i < 8; ++i) out_fs[ob + eb + i * 256] = S[i];
}

// ---------------- output: Y_diag + Y_off -> y written in place into x_bf ----------------
__global__ __launch_bounds__(256)
void ssd_out_kernel(bf16* __restrict__ x_bf, const bf16* __restrict__ B_bf,
                    const bf16* __restrict__ C_bf, const float* __restrict__ dts,
                    const float* __restrict__ acs_g, const bf16* __restrict__ states_g) {
  __shared__ bf16 Cs[64 * 128];     // [l][n]
  __shared__ bf16 BsMs[64 * 128];   // [s][n]; first 8KB reused as Ms[l][s]
  __shared__ bf16 xT[64 * 64];      // [p][l]
  __shared__ bf16 Sp[64 * 128];     // [p][n]
  __shared__ float acs_s[64];
  int blk = blockIdx.x;
  int h = blk & 63, c = (blk >> 6) & 63, b = blk >> 12;
  int t = threadIdx.x, lane = t & 63, wid = t >> 6;
  int tokBase = b * SEQ + c * 64;
  size_t sbase = ((size_t)((b * 64 + c) * 64 + h)) * 8192;

  if (t < 64) acs_s[t] = acs_g[(((size_t)(b * 64 + c)) * 64 + h) * 64 + t];
#pragma unroll
  for (int i = 0; i < 4; ++i) {                         // C, B natural
    int chunk = t + i * 256;
    int l = chunk >> 4, n0 = (chunk & 15) * 8;
    *(short8*)(Cs + l * 128 + n0) = *(const short8*)(C_bf + (size_t)(tokBase + l) * 128 + n0);
    *(short8*)(BsMs + l * 128 + n0) = *(const short8*)(B_bf + (size_t)(tokBase + l) * 128 + n0);
  }
#pragma unroll
  for (int i = 0; i < 2; ++i) {                         // x transpose (+ dt scale)
    int chunk = t + i * 256;
    int l = chunk >> 3, p0 = (chunk & 7) * 8;
    float dtv = dts[(size_t)(tokBase + l) * 64 + h];
    short8 vv = *(const short8*)(x_bf + (size_t)(tokBase + l) * 4096 + h * 64 + p0);
    const bf16* pv = (const bf16*)&vv;
#pragma unroll
    for (int j = 0; j < 8; ++j)
      xT[(p0 + j) * 64 + l] = __float2bfloat16(__bfloat162float(pv[j]) * dtv);
  }
#pragma unroll
  for (int i = 0; i < 4; ++i) {                         // S_prev bf16 -> LDS
    int chunk = t + i * 256;
    *(short8*)(Sp + chunk * 8) = *(const short8*)(states_g + sbase + chunk * 8);
  }
  __syncthreads();

  // G = C * B^T  (64x64, K=128)
  int lBase = (wid >> 1) * 32, sBase = (wid & 1) * 32;
  f32x4 g[2][2] = {};
#pragma unroll
  for (int ks = 0; ks < 4; ++ks) {
    short8 a[2], bb[2];
#pragma unroll
    for (int mi = 0; mi < 2; ++mi)
      a[mi] = *(const short8*)(Cs + (lBase + mi * 16 + (lane & 15)) * 128 + ks * 32 + (lane >> 4) * 8);
#pragma unroll
    for (int ni = 0; ni < 2; ++ni)
      bb[ni] = *(const short8*)(BsMs + (sBase + ni * 16 + (lane & 15)) * 128 + ks * 32 + (lane >> 4) * 8);
#pragma unroll
    for (int mi = 0; mi < 2; ++mi)
#pragma unroll
      for (int ni = 0; ni < 2; ++ni)
        g[mi][ni] = __builtin_amdgcn_mfma_f32_16x16x32_bf16(a[mi], bb[ni], g[mi][ni], 0, 0, 0);
  }
  __syncthreads();

  bf16* Ms = BsMs;                  // overwrite B region with masked scores
#pragma unroll
  for (int mi = 0; mi < 2; ++mi)
#pragma unroll
    for (int ni = 0; ni < 2; ++ni)
#pragma unroll
      for (int r = 0; r < 4; ++r) {
        int row = lBase + mi * 16 + (lane >> 4) * 4 + r;
        int col = sBase + ni * 16 + (lane & 15);
        float lm = (row >= col) ? expf(acs_s[row] - acs_s[col]) : 0.f;
        Ms[row * 64 + col] = __float2bfloat16(g[mi][ni][r] * lm);
      }
  __syncthreads();

  // Y_diag = Ms @ x  (K=64 over s),  Y_off = Cs @ Sp^T (K=128 over n)
  int pBase = (wid & 1) * 32;
  f32x4 yd[2][2] = {}, yo[2][2] = {};
#pragma unroll
  for (int ks = 0; ks < 2; ++ks) {
    short8 a[2], bb[2];
#pragma unroll
    for (int mi = 0; mi < 2; ++mi)
      a[mi] = *(const short8*)(Ms + (lBase + mi * 16 + (lane & 15)) * 64 + ks * 32 + (lane >> 4) * 8);
#pragma unroll
    for (int ni = 0; ni < 2; ++ni)
      bb[ni] = *(const short8*)(xT + (pBase + ni * 16 + (lane & 15)) * 64 + ks * 32 + (lane >> 4) * 8);
#pragma unroll
    for (int mi = 0; mi < 2; ++mi)
#pragma unroll
      for (int ni = 0; ni < 2; ++ni)
        yd[mi][ni] = __builtin_amdgcn_mfma_f32_16x16x32_bf16(a[mi], bb[ni], yd[mi][ni], 0, 0, 0);
  }
#pragma unroll
  for (int ks = 0; ks < 4; ++ks) {
    short8 a[2], bb[2];
#pragma unroll
    for (int mi = 0; mi < 2; ++mi)
      a[mi] = *(const short8*)(Cs + (lBase + mi * 16 + (lane & 15)) * 128 + ks * 32 + (lane >> 4) * 8);
#pragma unroll
    for (int ni = 0; ni < 2; ++ni)
      bb[ni] = *(const short8*)(Sp + (pBase + ni * 16 + (lane & 15)) * 128 + ks * 32 + (lane >> 4) * 8);
#pragma unroll
    for (int mi = 0; mi < 2; ++mi)
#pragma unroll
      for (int ni = 0; ni < 2; ++ni)
        yo[mi][ni] = __builtin_amdgcn_mfma_f32_16x16x32_bf16(a[mi], bb[ni], yo[mi][ni], 0, 0, 0);
  }
  __syncthreads();                  // all xT reads done before in-place write
#pragma unroll
  for (int mi = 0; mi < 2; ++mi)
#pragma unroll
    for (int ni = 0; ni < 2; ++ni)
#pragma unroll
      for (int r = 0; r < 4; ++r) {
        int lr = lBase + mi * 16 + (lane >> 4) * 4 + r;
        int p = pBase + ni * 16 + (lane & 15);
        float val = yd[mi][ni][r] + expf(acs_s[lr]) * yo[mi][ni][r];
        x_bf[(size_t)(tokBase + lr) * 4096 + h * 64 + p] = __float2bfloat16(val);
      }
}

// ---------------- launch ----------------
extern "C" void kernel_launch(void* const* d_in, const int* in_sizes, int n_in,
                              void* d_out, int out_size, void* d_ws, size_t ws_size,
                              hipStream_t stream) {
  const float* u       = (const float*)d_in[0];
  const float* W_in    = (const float*)d_in[1];
  const float* b_in    = (const float*)d_in[2];
  const float* W_out   = (const float*)d_in[3];
  const float* b_out   = (const float*)d_in[4];
  const float* A_log   = (const float*)d_in[5];
  const float* dt_bias = (const float*)d_in[6];

  float* y_out  = (float*)d_out;
  float* fs_out = y_out + (size_t)NTOK * MODEL_DIM;

  char* ws = (char*)d_ws;
  size_t off = 0;
  auto alloc = [&](size_t bytes) { char* p = ws + off; off += (bytes + 255) & ~255ull; return p; };
  bf16*  wout_bf = (bf16*) alloc((size_t)MODEL_DIM * INNER * 2);   // 16.8 MB
  bf16*  x_bf    = (bf16*) alloc((size_t)NTOK * INNER * 2);        // 67 MB (x, then y)
  bf16*  B_bf    = (bf16*) alloc((size_t)NTOK * STATE_DIM * 2);
  bf16*  C_bf    = (bf16*) alloc((size_t)NTOK * STATE_DIM * 2);
  float* dtraw   = (float*)alloc((size_t)NTOK * NHEADS * 4);
  float* dts     = (float*)alloc((size_t)NTOK * NHEADS * 4);
  float* a_dt    = (float*)alloc((size_t)NTOK * NHEADS * 4);
  float* acs     = (float*)alloc((size_t)BSZ * NCHUNK * NHEADS * 64 * 4);
  // region Q: states (bf16, 134 MB) aliased with {u_bf, win_bf} (dead after gemm_in)
  char*  Q       = alloc((size_t)BSZ * NCHUNK * NHEADS * 64 * 128 * 2);
  bf16*  states  = (bf16*)Q;
  bf16*  u_bf    = (bf16*)Q;
  bf16*  win_bf  = u_bf + (size_t)NTOK * MODEL_DIM;
  (void)ws_size; (void)off; (void)in_sizes; (void)n_in; (void)out_size;

  conv_f32_to_bf16<<<dim3(16384), dim3(256), 0, stream>>>(u, u_bf, NTOK * MODEL_DIM / 4);
  conv_win_pad<<<dim3(NPAD * MODEL_DIM / 1024), dim3(256), 0, stream>>>(W_in, win_bf);
  conv_f32_to_bf16<<<dim3(8192), dim3(256), 0, stream>>>(W_out, wout_bf, MODEL_DIM * INNER / 4);

  gemm_in256<<<dim3((NTOK / 256) * (NPAD / 192)), dim3(512), 0, stream>>>(
      u_bf, win_bf, b_in, x_bf, B_bf, C_bf, dtraw);

  prep_small<<<dim3(NTOK * NHEADS / 256), dim3(256), 0, stream>>>(dtraw, A_log, dt_bias, dts, a_dt);

  ssd_states_kernel<<<dim3(BSZ * NCHUNK * NHEADS), dim3(256), 0, stream>>>(
      x_bf, B_bf, dts, a_dt, acs, states);

  ssd_scan_kernel<<<dim3(BSZ * NHEADS * 4), dim3(256), 0, stream>>>(states, acs, fs_out);

  ssd_out_kernel<<<dim3(BSZ * NCHUNK * NHEADS), dim3(256), 0, stream>>>(
      x_bf, B_bf, C_bf, dts, acs, states);

  gemm_out256<<<dim3((MODEL_DIM / 256) * (NTOK / 256)), dim3(512), 0, stream>>>(
      x_bf, wout_bf, b_out, y_out);
}